// Round 9
// baseline (464.057 us; speedup 1.0000x reference)
//
#include <hip/hip_runtime.h>
#include <hip/hip_bf16.h>
#include <cmath>

typedef float f32x4 __attribute__((ext_vector_type(4)));
typedef __bf16 bf16x8 __attribute__((ext_vector_type(8)));
typedef __bf16 bf16x4 __attribute__((ext_vector_type(4)));

#define WS_SZ 7
#define SHIFT 3
#define HGRID 56
#define C_DIM 192
#define NHEADS 6
#define HDIM 32
#define NTOK 100352   // 32 * 3136
#define NWIN 2048     // 32 * 8 * 8

// map window-space row (w*49+i) -> original token index (inverse roll by +SHIFT)
__device__ __forceinline__ int win_to_tok(int wrow) {
    int w = wrow / 49, i = wrow - w * 49;
    int b = w >> 6, rem = w & 63;
    int wy = rem >> 3, wx = rem & 7;
    int yi = i / 7, xi = i - yi * 7;
    int y = wy * 7 + yi + SHIFT; if (y >= HGRID) y -= HGRID;
    int x = wx * 7 + xi + SHIFT; if (x >= HGRID) x -= HGRID;
    return b * (HGRID * HGRID) + y * HGRID + x;
}

// ---------------- fused fp32 -> bf16 conversion for ALL four weights --------------
// qkv 13824 x8, proj 4608 x8, fc1 18432 x8, fc2 18432 x8  => 55296 threads
__global__ __launch_bounds__(256)
void cvt_all_kernel(const float* __restrict__ qkvw, const float* __restrict__ projw,
                    const float* __restrict__ fc1w, const float* __restrict__ fc2w,
                    __bf16* __restrict__ qkvw_b, __bf16* __restrict__ projw_b,
                    __bf16* __restrict__ fc1w_b, __bf16* __restrict__ fc2w_b)
{
    int idx = blockIdx.x * 256 + threadIdx.x;
    if (idx >= 55296) return;
    const float* src; __bf16* dst; int off;
    if (idx < 13824)      { src = qkvw;  dst = qkvw_b;  off = idx; }
    else if (idx < 18432) { src = projw; dst = projw_b; off = idx - 13824; }
    else if (idx < 36864) { src = fc1w;  dst = fc1w_b;  off = idx - 18432; }
    else                  { src = fc2w;  dst = fc2w_b;  off = idx - 36864; }
    float4 a = ((const float4*)src)[off * 2];
    float4 b = ((const float4*)src)[off * 2 + 1];
    bf16x8 o;
    o[0] = (__bf16)a.x; o[1] = (__bf16)a.y; o[2] = (__bf16)a.z; o[3] = (__bf16)a.w;
    o[4] = (__bf16)b.x; o[5] = (__bf16)b.y; o[6] = (__bf16)b.z; o[7] = (__bf16)b.w;
    ((bf16x8*)dst)[off] = o;
}

// ---------------- expand rel-pos bias -> bias_g[head][49][49] fp32 ----------------
__global__ __launch_bounds__(256)
void bias_expand_kernel(const float* __restrict__ rpb, float* __restrict__ bias_g)
{
    int idx = blockIdx.x * 256 + threadIdx.x;
    if (idx >= NHEADS * 2401) return;
    int h = idx / 2401, rem = idx - h * 2401;
    int i = rem / 49, j = rem - i * 49;
    int yi = i / 7, xi = i - yi * 7;
    int yj = j / 7, xj = j - yj * 7;
    int ri = (yi - yj + 6) * 13 + (xi - xj + 6);
    bias_g[idx] = rpb[ri * NHEADS + h];
}

// ---------------- LayerNorm (one wave per token) ----------------
template<int WINDOWED>
__global__ __launch_bounds__(256)
void ln_kernel(const float* __restrict__ x, const float* __restrict__ w,
               const float* __restrict__ b, __bf16* __restrict__ out)
{
    int r = blockIdx.x * 4 + (threadIdx.x >> 6);
    int lane = threadIdx.x & 63;
    int src = WINDOWED ? win_to_tok(r) : r;
    const float* xp = x + (size_t)src * C_DIM;
    float v0 = xp[lane], v1 = xp[lane + 64], v2 = xp[lane + 128];
    float s = v0 + v1 + v2;
    float sq = v0 * v0 + v1 * v1 + v2 * v2;
    #pragma unroll
    for (int off = 32; off; off >>= 1) {
        s  += __shfl_xor(s, off);
        sq += __shfl_xor(sq, off);
    }
    float mu = s * (1.f / C_DIM);
    float rs = rsqrtf(sq * (1.f / C_DIM) - mu * mu + 1e-5f);
    __bf16* op = out + (size_t)r * C_DIM;
    op[lane]       = (__bf16)((v0 - mu) * rs * w[lane]       + b[lane]);
    op[lane + 64]  = (__bf16)((v1 - mu) * rs * w[lane + 64]  + b[lane + 64]);
    op[lane + 128] = (__bf16)((v2 - mu) * rs * w[lane + 128] + b[lane + 128]);
}

// ---------------- GEMM (QKV): out = A @ W^T + bias, store bf16 --------------------
__global__ __launch_bounds__(256)
void gemm_kernel(const __bf16* __restrict__ A, const __bf16* __restrict__ W,
                 const float* __restrict__ bias, __bf16* __restrict__ outp,
                 int N, int K)
{
    __shared__ __bf16 As[128 * 40];
    __shared__ __bf16 Bs[64 * 40];
    const int tid = threadIdx.x;
    const int wave = tid >> 6, lane = tid & 63;
    const int wm = wave >> 1, wn = wave & 1;
    const int l15 = lane & 15, q8 = (lane >> 4) << 3;
    const int m0 = blockIdx.y * 128, n0 = blockIdx.x * 64;

    f32x4 acc[4][2];
    f32x4 zero = {0.f, 0.f, 0.f, 0.f};
    #pragma unroll
    for (int i = 0; i < 4; i++)
        #pragma unroll
        for (int j = 0; j < 2; j++) acc[i][j] = zero;

    const int br = tid >> 2, bc = (tid & 3) << 3;
    for (int kt = 0; kt < K; kt += 32) {
        __syncthreads();
        #pragma unroll
        for (int it = 0; it < 2; it++) {
            int idx = it * 256 + tid;
            int r = idx >> 2, c = (idx & 3) << 3;
            *(uint4*)(&As[r * 40 + c]) =
                *(const uint4*)(A + (size_t)(m0 + r) * K + kt + c);
        }
        *(uint4*)(&Bs[br * 40 + bc]) =
            *(const uint4*)(W + (size_t)(n0 + br) * K + kt + bc);
        __syncthreads();
        bf16x8 af[4], bfr[2];
        #pragma unroll
        for (int fm = 0; fm < 4; fm++)
            af[fm] = *(const bf16x8*)(&As[(wm * 64 + fm * 16 + l15) * 40 + q8]);
        #pragma unroll
        for (int fn = 0; fn < 2; fn++)
            bfr[fn] = *(const bf16x8*)(&Bs[(wn * 32 + fn * 16 + l15) * 40 + q8]);
        #pragma unroll
        for (int fm = 0; fm < 4; fm++)
            #pragma unroll
            for (int fn = 0; fn < 2; fn++)
                acc[fm][fn] = __builtin_amdgcn_mfma_f32_16x16x32_bf16(
                    af[fm], bfr[fn], acc[fm][fn], 0, 0, 0);
    }

    const int l4 = lane >> 4;
    #pragma unroll
    for (int fm = 0; fm < 4; fm++) {
        #pragma unroll
        for (int fn = 0; fn < 2; fn++) {
            int c = n0 + wn * 32 + fn * 16 + l15;
            float bv = bias[c];
            #pragma unroll
            for (int r = 0; r < 4; r++) {
                int m = m0 + wm * 64 + fm * 16 + l4 * 4 + r;
                outp[(size_t)m * N + c] = (__bf16)(acc[fm][fn][r] + bv);
            }
        }
    }
}

// ---------------- Fused proj + residual + LN2: ------------------------------------
// Block = 64 window rows, 4 waves; wave wn owns rows [wn*16,+16) x all 192 cols
// (acc[12] = 48 VGPR, the proven mlp-GEMM2 fragment shape). projw staged in LDS
// per K-step. Epilogue (per 32-row pass): acc+bias -> Cs (LDS transpose), then
// all 256 threads: residual(+x) -> coalesced out store -> in-LDS row LN
// (8 thr/row, 3 shuffles) -> coalesced bf16 store to lnout (token space).
__global__ __launch_bounds__(256, 3)
void proj_ln_kernel(const __bf16* __restrict__ A,   // bufA: NTOK x 192 (attn out, window rows)
                    const __bf16* __restrict__ W,   // projw_b: 192 x 192
                    const float* __restrict__ pb,   // projb
                    const float* __restrict__ x,    // residual (token space)
                    const float* __restrict__ n2w, const float* __restrict__ n2b,
                    float* __restrict__ out,        // fp32, token space
                    __bf16* __restrict__ lnout)     // bf16 LN2 result, token space
{
    __shared__ __align__(16) __bf16 As[64 * 200];   // 25600B; reused as Cs[32][196] fp32
    __shared__ __bf16 Bs[192 * 40];                 // 15360B
    const int tid = threadIdx.x;
    const int wn = tid >> 6, lane = tid & 63;
    const int l15 = lane & 15, q4 = lane >> 4, q8 = q4 << 3;
    const int m0 = blockIdx.x * 64;

    // bias per (tn): col = tn*16 + l15
    float bvp[12];
    #pragma unroll
    for (int tn = 0; tn < 12; ++tn) bvp[tn] = pb[tn * 16 + l15];

    // stage A tile 64x192 (6 x 16B per thread)
    #pragma unroll
    for (int it = 0; it < 6; ++it) {
        int idx = it * 256 + tid;
        int r = idx / 24, c = (idx - r * 24) << 3;
        *(uint4*)(&As[r * 200 + c]) =
            *(const uint4*)(A + (size_t)(m0 + r) * 192 + c);
    }

    f32x4 zero = {0.f, 0.f, 0.f, 0.f};
    f32x4 acc[12];
    #pragma unroll
    for (int tn = 0; tn < 12; ++tn) acc[tn] = zero;

    const int br = tid >> 2, bc = (tid & 3) << 3;   // Bs staging: 3 rounds
    for (int kt = 0; kt < 6; ++kt) {
        __syncthreads();        // As staged (kt=0) / prior Bs reads done
        #pragma unroll
        for (int it = 0; it < 3; ++it) {
            int r = br + it * 64;    // wait: idx-based
            int idx = it * 256 + tid;
            int rr = idx >> 2, cc = (idx & 3) << 3;
            *(uint4*)(&Bs[rr * 40 + cc]) =
                *(const uint4*)(W + (size_t)rr * 192 + kt * 32 + cc);
        }
        __syncthreads();
        bf16x8 af = *(const bf16x8*)(&As[(wn * 16 + l15) * 200 + kt * 32 + q8]);
        #pragma unroll
        for (int tn = 0; tn < 12; ++tn) {
            bf16x8 bfr = *(const bf16x8*)(&Bs[(tn * 16 + l15) * 40 + q8]);
            acc[tn] = __builtin_amdgcn_mfma_f32_16x16x32_bf16(af, bfr, acc[tn], 0, 0, 0);
        }
    }

    // ---- epilogue: two 32-row passes through Cs (reuses As region) ----
    float* Cs = (float*)As;     // 32 * 196 * 4 = 25088 B
    const int rowt = tid >> 3, lane8 = tid & 7;   // 32 rows x 8 threads
    const int c0 = lane8 * 24;
    #pragma unroll
    for (int pass = 0; pass < 2; ++pass) {
        __syncthreads();        // pass0: all MFMA/ds reads done; pass1: reads done
        if ((wn >> 1) == pass) {
            int rl0 = (wn & 1) * 16 + q4 * 4;     // local rows rl0..rl0+3
            #pragma unroll
            for (int tn = 0; tn < 12; ++tn) {
                int c = tn * 16 + l15;
                #pragma unroll
                for (int r = 0; r < 4; ++r)
                    Cs[(rl0 + r) * 196 + c] = acc[tn][r] + bvp[tn];
            }
        }
        __syncthreads();
        // all threads: row = rowt (0..31), cols c0..c0+24
        int m = m0 + pass * 32 + rowt;
        int t = win_to_tok(m);
        const float* xp = x + (size_t)t * C_DIM + c0;
        float* op = out + (size_t)t * C_DIM + c0;
        float v[24];
        float s = 0.f, sq = 0.f;
        #pragma unroll
        for (int e = 0; e < 24; ++e) {
            float o = xp[e] + Cs[rowt * 196 + c0 + e];
            v[e] = o;
            s += o; sq += o * o;
        }
        // write out (fp32, coalesced: 6 float4 per thread, row-contiguous)
        #pragma unroll
        for (int e4 = 0; e4 < 6; ++e4) {
            float4 g = { v[e4*4], v[e4*4+1], v[e4*4+2], v[e4*4+3] };
            *(float4*)(op + e4 * 4) = g;
        }
        // row LN: reduce across the 8 lanes of this row
        s  += __shfl_xor(s, 1);  s  += __shfl_xor(s, 2);  s  += __shfl_xor(s, 4);
        sq += __shfl_xor(sq, 1); sq += __shfl_xor(sq, 2); sq += __shfl_xor(sq, 4);
        float mu = s * (1.f / C_DIM);
        float rs = rsqrtf(sq * (1.f / C_DIM) - mu * mu + 1e-5f);
        __bf16* lp = lnout + (size_t)t * C_DIM + c0;
        #pragma unroll
        for (int e8 = 0; e8 < 3; ++e8) {
            bf16x8 ob;
            #pragma unroll
            for (int e = 0; e < 8; ++e) {
                int c = c0 + e8 * 8 + e;
                ob[e] = (__bf16)((v[e8*8+e] - mu) * rs * n2w[c] + n2b[c]);
            }
            *(bf16x8*)(lp + e8 * 8) = ob;
        }
    }
}

// ---------------- Fused MLP (R4 chunk loop; prologue = bf16 staging copy) --------
__global__ __launch_bounds__(256, 3)
void mlp_fused_kernel(const __bf16* __restrict__ lnA,  // NTOK x 192 bf16 (LN2 done)
                      const __bf16* __restrict__ w1,   // 768 x 192
                      const float* __restrict__ b1,
                      const __bf16* __restrict__ w2,   // 192 x 768
                      const float* __restrict__ b2,
                      float* __restrict__ out)         // NTOK x 192 fp32, RMW
{
    __shared__ __align__(16) __bf16 As[64 * 200]; // 25600B; reused as fp32 Cs[32][196]
    __shared__ __bf16 Hs[64 * 72];                // 9216B
    const int tid = threadIdx.x;
    const int wn = tid >> 6, lane = tid & 63;
    const int l15 = lane & 15, q4 = lane >> 4, q8 = q4 << 3;
    const int m0 = blockIdx.x * 64;

    const __bf16* w1base = w1 + (size_t)(wn * 16 + l15) * 192 + q8;
    const __bf16* w2base = w2 + (size_t)(wn * 48 + l15) * 768 + q8;

    f32x4 zero = {0.f, 0.f, 0.f, 0.f};

    // prefetch W1 frags for chunk 0 (in flight during staging)
    bf16x8 w1f[2][6];
    #pragma unroll
    for (int kt = 0; kt < 6; ++kt)
        w1f[0][kt] = *(const bf16x8*)(w1base + kt * 32);

    // per-chunk b1 scalars and b2 scalars
    float bv1s[12];
    #pragma unroll
    for (int ch = 0; ch < 12; ++ch)
        bv1s[ch] = b1[ch * 64 + wn * 16 + l15];
    float bv2s[3];
    #pragma unroll
    for (int tn = 0; tn < 3; ++tn)
        bv2s[tn] = b2[wn * 48 + tn * 16 + l15];

    // ---- prologue: stage LN2'd A tile (64x192 bf16), coalesced ----
    #pragma unroll
    for (int it = 0; it < 6; ++it) {
        int idx = it * 256 + tid;
        int r = idx / 24, c = (idx - r * 24) << 3;
        *(uint4*)(&As[r * 200 + c]) =
            *(const uint4*)(lnA + (size_t)(m0 + r) * 192 + c);
    }
    __syncthreads();

    f32x4 acc2[4][3];
    #pragma unroll
    for (int tm = 0; tm < 4; ++tm)
        #pragma unroll
        for (int tn = 0; tn < 3; ++tn) acc2[tm][tn] = zero;

    bf16x8 w2f[6];

    #pragma unroll
    for (int ch = 0; ch < 12; ++ch) {
        const int h0 = ch * 64;
        const int cur = ch & 1, nxt = cur ^ 1;

        if (ch < 11) {
            #pragma unroll
            for (int kt = 0; kt < 6; ++kt)
                w1f[nxt][kt] = *(const bf16x8*)(w1base + (size_t)(h0 + 64) * 192 + kt * 32);
        }
        #pragma unroll
        for (int ks = 0; ks < 2; ++ks)
            #pragma unroll
            for (int tn = 0; tn < 3; ++tn)
                w2f[ks * 3 + tn] = *(const bf16x8*)(w2base + (size_t)(tn * 16) * 768 + h0 + ks * 32);

        // ---- GEMM1
        f32x4 acc1[4];
        #pragma unroll
        for (int tm = 0; tm < 4; ++tm) acc1[tm] = zero;
        #pragma unroll
        for (int kt = 0; kt < 6; ++kt)
            #pragma unroll
            for (int tm = 0; tm < 4; ++tm) {
                bf16x8 af = *(const bf16x8*)(&As[(tm * 16 + l15) * 200 + kt * 32 + q8]);
                acc1[tm] = __builtin_amdgcn_mfma_f32_16x16x32_bf16(
                    af, w1f[cur][kt], acc1[tm], 0, 0, 0);
            }

        __syncthreads();

        // ---- GELU -> Hs
        {
            const float bv = bv1s[ch];
            #pragma unroll
            for (int tm = 0; tm < 4; ++tm)
                #pragma unroll
                for (int r = 0; r < 4; ++r) {
                    int row = tm * 16 + q4 * 4 + r;
                    float v = acc1[tm][r] + bv;
                    float g = v * __builtin_amdgcn_rcpf(1.f + __expf(-1.702f * v));
                    Hs[row * 72 + wn * 16 + l15] = (__bf16)g;
                }
        }
        __syncthreads();

        // ---- GEMM2
        #pragma unroll
        for (int ks = 0; ks < 2; ++ks)
            #pragma unroll
            for (int tm = 0; tm < 4; ++tm) {
                bf16x8 ap = *(const bf16x8*)(&Hs[(tm * 16 + l15) * 72 + ks * 32 + q8]);
                #pragma unroll
                for (int tn = 0; tn < 3; ++tn)
                    acc2[tm][tn] = __builtin_amdgcn_mfma_f32_16x16x32_bf16(
                        ap, w2f[ks * 3 + tn], acc2[tm][tn], 0, 0, 0);
            }
    }

    // ---- epilogue: coalesced RMW via LDS transpose ----
    float* Cs = (float*)As;
    #pragma unroll
    for (int pass = 0; pass < 2; ++pass) {
        if (pass) __syncthreads();
        #pragma unroll
        for (int tmh = 0; tmh < 2; ++tmh) {
            int tm = pass * 2 + tmh;
            #pragma unroll
            for (int tn = 0; tn < 3; ++tn) {
                int c = wn * 48 + tn * 16 + l15;
                float bv = bv2s[tn];
                #pragma unroll
                for (int r = 0; r < 4; ++r) {
                    int rl = tmh * 16 + q4 * 4 + r;
                    Cs[rl * 196 + c] = acc2[tm][tn][r] + bv;
                }
            }
        }
        __syncthreads();
        #pragma unroll
        for (int it = 0; it < 6; ++it) {
            int f = it * 256 + tid;
            int row = f / 48, c4 = f - row * 48;
            float4* gp = (float4*)(out + (size_t)(m0 + pass * 32 + row) * C_DIM) + c4;
            float4 g = *gp;
            const float* lp = &Cs[row * 196 + c4 * 4];
            g.x += lp[0]; g.y += lp[1]; g.z += lp[2]; g.w += lp[3];
            *gp = g;
        }
    }
}

// ---------------- MFMA windowed attention: one wave per block (R8) ---------------
__global__ __launch_bounds__(64)
void attn_mfma_kernel(const __bf16* __restrict__ qkv,
                      const float* __restrict__ bias_g,
                      __bf16* __restrict__ out)
{
    const int lane = threadIdx.x & 63;
    const int pair = blockIdx.x;                  // 12288 pairs
    const int w = pair / 6, head = pair - (pair / 6) * 6;

    __shared__ __bf16 vsT[32 * 72];               // V^T: [d][j], stride 72
    __shared__ __bf16 Ps[64 * 72];                // P:   [i][j], stride 72

    const int l15 = lane & 15, q4 = lane >> 4, q8 = q4 << 3;
    const size_t qbase = (size_t)w * 49 * 576 + head * 32;

    bf16x8 qf[4], kf[4];
    #pragma unroll
    for (int t = 0; t < 4; ++t) {
        int row = t * 16 + l15;
        int rq = row < 49 ? row : 48;
        qf[t] = *(const bf16x8*)(qkv + qbase + (size_t)rq * 576 + q8);
        kf[t] = *(const bf16x8*)(qkv + qbase + (size_t)rq * 576 + 192 + q8);
    }

    {
        int j0 = lane >> 2, dq = (lane & 3) << 3;
        #pragma unroll
        for (int p = 0; p < 4; ++p) {
            int j = p * 16 + j0;
            if (j < 49) {
                bf16x8 vv = *(const bf16x8*)(qkv + qbase + (size_t)j * 576 + 384 + dq);
                #pragma unroll
                for (int e = 0; e < 8; ++e)
                    vsT[(dq + e) * 72 + j] = vv[e];
            }
        }
        for (int idx = lane; idx < 32 * 15; idx += 64) {
            int dd = idx / 15, jj = 49 + (idx - dd * 15);
            vsT[dd * 72 + jj] = (__bf16)0.f;
        }
    }

    f32x4 sc[4][4];
    f32x4 zero = {0.f, 0.f, 0.f, 0.f};
    #pragma unroll
    for (int tn = 0; tn < 4; ++tn)
        #pragma unroll
        for (int tm = 0; tm < 4; ++tm) sc[tn][tm] = zero;
    __builtin_amdgcn_s_setprio(1);
    #pragma unroll
    for (int tn = 0; tn < 4; ++tn)
        #pragma unroll
        for (int tm = 0; tm < 4; ++tm)
            sc[tn][tm] = __builtin_amdgcn_mfma_f32_16x16x32_bf16(
                kf[tn], qf[tm], sc[tn][tm], 0, 0, 0);
    __builtin_amdgcn_s_setprio(0);

    const float scale = 0.17677669529663687f;      // 1/sqrt(32)
    const int hbase = head * 2401;
    const int jb4 = q4 * 4;
    #pragma unroll
    for (int tm = 0; tm < 4; ++tm) {
        int i = tm * 16 + l15;
        int ioff = hbase + (i < 49 ? i : 48) * 49;
        float v[4][4];
        #pragma unroll
        for (int tn = 0; tn < 4; ++tn) {
            int jb = tn * 16 + jb4;
            #pragma unroll
            for (int r = 0; r < 4; ++r) {
                int j = jb + r;
                float bz = (j < 49) ? bias_g[ioff + j] : 0.f;
                float t = sc[tn][tm][r] * scale + bz;
                v[tn][r] = (j < 49) ? t : -1e30f;
            }
        }
        float mx = v[0][0];
        #pragma unroll
        for (int tn = 0; tn < 4; ++tn)
            #pragma unroll
            for (int r = 0; r < 4; ++r) mx = fmaxf(mx, v[tn][r]);
        mx = fmaxf(mx, __shfl_xor(mx, 16));
        mx = fmaxf(mx, __shfl_xor(mx, 32));
        float sm = 0.f;
        #pragma unroll
        for (int tn = 0; tn < 4; ++tn)
            #pragma unroll
            for (int r = 0; r < 4; ++r) {
                float e = __expf(v[tn][r] - mx);
                v[tn][r] = e;
                sm += e;
            }
        sm += __shfl_xor(sm, 16);
        sm += __shfl_xor(sm, 32);
        float inv = __builtin_amdgcn_rcpf(sm);
        if (i < 49) {
            #pragma unroll
            for (int tn = 0; tn < 4; ++tn) {
                int jb = tn * 16 + jb4;
                bf16x4 pk;
                #pragma unroll
                for (int r = 0; r < 4; ++r)
                    pk[r] = (__bf16)((jb + r < 49) ? v[tn][r] * inv : 0.f);
                *(bf16x4*)(&Ps[i * 72 + jb]) = pk;
            }
        }
    }

    f32x4 oc[4][2];
    #pragma unroll
    for (int tm = 0; tm < 4; ++tm)
        #pragma unroll
        for (int tn = 0; tn < 2; ++tn) oc[tm][tn] = zero;
    #pragma unroll
    for (int ks = 0; ks < 2; ++ks) {
        bf16x8 bv[2];
        #pragma unroll
        for (int tn = 0; tn < 2; ++tn)
            bv[tn] = *(const bf16x8*)(vsT + (tn * 16 + l15) * 72 + ks * 32 + q8);
        __builtin_amdgcn_s_setprio(1);
        #pragma unroll
        for (int tm = 0; tm < 4; ++tm) {
            bf16x8 ap = *(const bf16x8*)(Ps + (tm * 16 + l15) * 72 + ks * 32 + q8);
            #pragma unroll
            for (int tn = 0; tn < 2; ++tn)
                oc[tm][tn] = __builtin_amdgcn_mfma_f32_16x16x32_bf16(
                    ap, bv[tn], oc[tm][tn], 0, 0, 0);
        }
        __builtin_amdgcn_s_setprio(0);
    }

    #pragma unroll
    for (int tm = 0; tm < 4; ++tm) {
        #pragma unroll
        for (int r = 0; r < 4; ++r) {
            int m = tm * 16 + q4 * 4 + r;
            if (m < 49) {
                __bf16* op = out + (size_t)(w * 49 + m) * C_DIM + head * 32;
                #pragma unroll
                for (int tn = 0; tn < 2; ++tn)
                    op[tn * 16 + l15] = (__bf16)(oc[tm][tn][r]);
            }
        }
    }
}

extern "C" void kernel_launch(void* const* d_in, const int* in_sizes, int n_in,
                              void* d_out, int out_size, void* d_ws, size_t ws_size,
                              hipStream_t stream) {
    const float* x     = (const float*)d_in[0];
    const float* n1w   = (const float*)d_in[1];
    const float* n1b   = (const float*)d_in[2];
    const float* qkvw  = (const float*)d_in[3];
    const float* qkvb  = (const float*)d_in[4];
    const float* rpb   = (const float*)d_in[5];
    const float* projw = (const float*)d_in[6];
    const float* projb = (const float*)d_in[7];
    const float* n2w   = (const float*)d_in[8];
    const float* n2b   = (const float*)d_in[9];
    const float* fc1w  = (const float*)d_in[10];
    const float* fc1b  = (const float*)d_in[11];
    const float* fc2w  = (const float*)d_in[12];
    const float* fc2b  = (const float*)d_in[13];
    float* out = (float*)d_out;
    char* ws = (char*)d_ws;

    // ws layout — regions disjoint; bufQ doubles as lnout AFTER attn consumed it:
    //   bufA    @ 0           : 100352*192 bf16 = 38,535,168
    //   bufQ    @ 38,535,168  : 100352*576 bf16 = 115,605,504 -> ends 154,140,672
    //           (proj_ln reuses first 38.5MB of bufQ as LN2-output, post-attn)
    //   qkvw_b  @ 154,140,672 : 221,184
    //   projw_b @ 154,361,856 : 73,728
    //   fc1w_b  @ 154,435,584 : 294,912
    //   fc2w_b  @ 154,730,496 : 294,912
    //   bias_g  @ 155,025,408 : 57,624   -> ends 155,083,032
    __bf16* bufA    = (__bf16*)ws;
    __bf16* bufQ    = (__bf16*)(ws + 38535168);
    __bf16* lnout   = bufQ;                    // aliased: valid only after attn
    __bf16* qkvw_b  = (__bf16*)(ws + 154140672);
    __bf16* projw_b = (__bf16*)(ws + 154361856);
    __bf16* fc1w_b  = (__bf16*)(ws + 154435584);
    __bf16* fc2w_b  = (__bf16*)(ws + 154730496);
    float*  bias_g  = (float*) (ws + 155025408);

    // 0. fused weight conversion + bias expansion
    cvt_all_kernel<<<216, 256, 0, stream>>>(qkvw, projw, fc1w, fc2w,
                                            qkvw_b, projw_b, fc1w_b, fc2w_b);
    bias_expand_kernel<<<(NHEADS*2401 + 255)/256, 256, 0, stream>>>(rpb, bias_g);

    // 1. LN1 + shift + window partition
    ln_kernel<1><<<NTOK / 4, 256, 0, stream>>>(x, n1w, n1b, bufA);
    // 2. QKV GEMM (n-fast grid for A-tile L2 reuse)
    gemm_kernel<<<dim3(9, NTOK / 128), 256, 0, stream>>>(
        bufA, qkvw_b, qkvb, bufQ, 576, 192);
    // 3. windowed attention (MFMA, 1 wave/block, swapped-QK^T softmax)
    attn_mfma_kernel<<<NWIN * NHEADS, 64, 0, stream>>>(bufQ, bias_g, bufA);
    // 4. proj GEMM + window reverse + residual + LN2 -> out (fp32) + lnout (bf16)
    proj_ln_kernel<<<NTOK / 64, 256, 0, stream>>>(
        bufA, projw_b, projb, x, n2w, n2b, out, lnout);
    // 5+6+7. fused MLP (FC1 + GELU + FC2 + residual), LN2 already done
    mlp_fused_kernel<<<NTOK / 64, 256, 0, stream>>>(
        lnout, fc1w_b, fc1b, fc2w_b, fc2b, out);
}